// Round 1
// baseline (356.872 us; speedup 1.0000x reference)
//
#include <hip/hip_runtime.h>

#define HW8 8
#define NSW 2
#define CBINS 8
#define NDCT 32
#define NF 64
#define KDIM 2048   // NDCT * 64 spatial
#define SLOPE 0.02f

// ---------------------------------------------------------------------------
// Kernel 1: precompute effective weights
// Veff[s,o,t,i,j] = 0.125 * sum_{f,p,q} Ct[f,t] Cs[p,i] Cs[q,j] W[s,o,f,p,q]
// One block per (s,o) pair: 128 blocks x 256 threads. Separable 3-stage DCT^T.
// ---------------------------------------------------------------------------
__global__ __launch_bounds__(256) void veff_kernel(const float* __restrict__ W,
                                                   float* __restrict__ Veff) {
    __shared__ float bufA[2048];
    __shared__ float bufB[2048];
    const int so = blockIdx.x;          // s*64 + o
    const int tid = threadIdx.x;
    const float PI = 3.14159265358979323846f;

    const float* Wso = W + so * 2048;   // [f(32)][p(8)][q(8)]
    for (int idx = tid; idx < 2048; idx += 256) bufA[idx] = Wso[idx];
    __syncthreads();

    // Stage A: contract f (32) with Ct[f,t] -> [t][pq]
    for (int idx = tid; idx < 2048; idx += 256) {
        int t = idx >> 6, pq = idx & 63;
        float ang0 = PI * (float)(2 * t + 1) / 64.0f;
        float s = 0.f;
        #pragma unroll 8
        for (int f = 0; f < 32; ++f)
            s += 2.0f * cosf(ang0 * (float)f) * bufA[f * 64 + pq];
        bufB[idx] = s;
    }
    __syncthreads();

    // Stage B: contract p (8) with Cs[p,i] -> [t][i][q]
    for (int idx = tid; idx < 2048; idx += 256) {
        int t = idx >> 6, i = (idx >> 3) & 7, q = idx & 7;
        float ang0 = PI * (float)(2 * i + 1) / 16.0f;
        float s = 0.f;
        #pragma unroll
        for (int p = 0; p < 8; ++p)
            s += 2.0f * cosf(ang0 * (float)p) * bufB[t * 64 + p * 8 + q];
        bufA[idx] = s;
    }
    __syncthreads();

    // Stage C: contract q (8) with Cs[q,j] -> [t][i][j]; fold in 1/8 (mean over c)
    for (int idx = tid; idx < 2048; idx += 256) {
        int t = idx >> 6, i = (idx >> 3) & 7, j = idx & 7;
        float ang0 = PI * (float)(2 * j + 1) / 16.0f;
        float s = 0.f;
        #pragma unroll
        for (int q = 0; q < 8; ++q)
            s += 2.0f * cosf(ang0 * (float)q) * bufA[t * 64 + i * 8 + q];
        Veff[so * 2048 + idx] = 0.125f * s;
    }
}

// ---------------------------------------------------------------------------
// Kernel 2: xsum[b,s,t,ij] = sum_{c=0..7} x[b, s*256 + c*32 + t, ij]
// float4-vectorized; fully coalesced. Memory-bound (reads 128 MiB).
// ---------------------------------------------------------------------------
__global__ __launch_bounds__(256) void reduce_c_kernel(const float* __restrict__ x,
                                                       float* __restrict__ xsum) {
    int g = blockIdx.x * 256 + threadIdx.x;   // one float4 output each
    int ij4 = g & 15;
    int t   = (g >> 4) & 31;
    int s   = (g >> 9) & 1;
    int b   = g >> 10;
    const float4* xp = (const float4*)x + ((b * 512 + s * 256 + t) * 16 + ij4);
    float4 acc = make_float4(0.f, 0.f, 0.f, 0.f);
    #pragma unroll
    for (int c = 0; c < 8; ++c) {
        float4 v = xp[c * 32 * 16];           // stride 32 time-points
        acc.x += v.x; acc.y += v.y; acc.z += v.z; acc.w += v.w;
    }
    ((float4*)xsum)[g] = acc;
}

// ---------------------------------------------------------------------------
// Kernel 3: feat[b,s,o] = dot(xsum[b,s,:], Veff[s,o,:]) + bias[s,o]; LeakyReLU.
// Tiled fp32 GEMM: block = (b-tile of 8) x (all 64 o) for one s.
// Grid: (128, 2) x 256 threads. Thread -> (bl = tid>>5, o = tid&31, o+32).
// ---------------------------------------------------------------------------
#define BT 8
#define KT 64
__global__ __launch_bounds__(256) void gemm_kernel(const float* __restrict__ xsum,
                                                   const float* __restrict__ Veff,
                                                   const float* __restrict__ bias,
                                                   float* __restrict__ out) {
    __shared__ float Xs[BT][KT];
    __shared__ float Vs[64][KT + 1];   // +1 pad: stride 65 -> conflict-free
    const int s  = blockIdx.y;
    const int b0 = blockIdx.x * BT;
    const int tid = threadIdx.x;
    const int o  = tid & 31;
    const int bl = tid >> 5;

    float acc0 = 0.f, acc1 = 0.f;
    for (int kt = 0; kt < KDIM; kt += KT) {
        for (int idx = tid; idx < BT * KT; idx += 256) {
            int bb = idx >> 6, kk = idx & 63;
            Xs[bb][kk] = xsum[((b0 + bb) * 2 + s) * KDIM + kt + kk];
        }
        for (int idx = tid; idx < 64 * KT; idx += 256) {
            int oo = idx >> 6, kk = idx & 63;
            Vs[oo][kk] = Veff[(s * 64 + oo) * KDIM + kt + kk];
        }
        __syncthreads();
        #pragma unroll
        for (int kk = 0; kk < KT; ++kk) {
            float xv = Xs[bl][kk];
            acc0 += xv * Vs[o][kk];
            acc1 += xv * Vs[o + 32][kk];
        }
        __syncthreads();
    }

    float f0 = acc0 + bias[s * 64 + o];
    float f1 = acc1 + bias[s * 64 + o + 32];
    f0 = (f0 >= 0.f) ? f0 : SLOPE * f0;
    f1 = (f1 >= 0.f) ? f1 : SLOPE * f1;
    out[(b0 + bl) * 128 + s * 64 + o]      = f0;
    out[(b0 + bl) * 128 + s * 64 + o + 32] = f1;
}

extern "C" void kernel_launch(void* const* d_in, const int* in_sizes, int n_in,
                              void* d_out, int out_size, void* d_ws, size_t ws_size,
                              hipStream_t stream) {
    const float* x    = (const float*)d_in[0];   // [B,1,512,8,8]
    const float* W    = (const float*)d_in[1];   // [2,64,32,8,8]
    const float* bias = (const float*)d_in[2];   // [2,64]
    float* out = (float*)d_out;                  // [B,128]

    const int B = in_sizes[0] / (512 * 64);      // 1024

    float* Veff = (float*)d_ws;                  // 2*64*2048 floats = 1 MiB
    float* xsum = Veff + NSW * NF * KDIM;        // B*2*2048 floats = 16 MiB

    veff_kernel<<<NSW * NF, 256, 0, stream>>>(W, Veff);

    int n4 = B * NSW * NDCT * 16;                // float4 outputs
    reduce_c_kernel<<<n4 / 256, 256, 0, stream>>>(x, xsum);

    gemm_kernel<<<dim3(B / BT, NSW), 256, 0, stream>>>(xsum, Veff, bias, out);
}

// Round 2
// 227.192 us; speedup vs baseline: 1.5708x; 1.5708x over previous
//
#include <hip/hip_runtime.h>

#define NSW 2
#define NDCT 32
#define NF 64
#define KDIM 2048          // 32 t * 64 spatial
#define SLOPE 0.02f
#define PI_F 3.14159265358979323846f

// ---------------------------------------------------------------------------
// Kernel 1: Veff[s,o,t,i,j] = 0.125 * sum_{f,p,q} Ct[f,t] Cs[p,i] Cs[q,j] W[s,o,f,p,q]
// cos tables built once in LDS (~1.1k cosf per block), then 3 pure-FMA stages.
// ---------------------------------------------------------------------------
__global__ __launch_bounds__(256) void veff_kernel(const float* __restrict__ W,
                                                   float* __restrict__ Veff) {
    __shared__ float Ct[32][32];   // [f][t] = 2*cos(pi*(2t+1)*f/64)
    __shared__ float Cs[8][8];     // [p][i] = 2*cos(pi*(2i+1)*p/16)
    __shared__ float bufA[2048];
    __shared__ float bufB[2048];
    const int tid = threadIdx.x;

    for (int idx = tid; idx < 1024; idx += 256) {
        int f = idx >> 5, t = idx & 31;
        Ct[f][t] = 2.0f * cosf(PI_F * (float)((2 * t + 1) * f) * (1.0f / 64.0f));
    }
    if (tid < 64) {
        int p = tid >> 3, i = tid & 7;
        Cs[p][i] = 2.0f * cosf(PI_F * (float)((2 * i + 1) * p) * (1.0f / 16.0f));
    }
    const float* Wso = W + blockIdx.x * 2048;   // [f(32)][p(8)][q(8)]
    for (int idx = tid; idx < 2048; idx += 256) bufA[idx] = Wso[idx];
    __syncthreads();

    // contract f: out[t][pq] = sum_f Ct[f][t] * W[f][pq]
    for (int idx = tid; idx < 2048; idx += 256) {
        int t = idx >> 6, pq = idx & 63;
        float s = 0.f;
        #pragma unroll
        for (int f = 0; f < 32; ++f) s += Ct[f][t] * bufA[f * 64 + pq];
        bufB[idx] = s;
    }
    __syncthreads();

    // contract p: out[t][i][q] = sum_p Cs[p][i] * in[t][p][q]
    for (int idx = tid; idx < 2048; idx += 256) {
        int t = idx >> 6, i = (idx >> 3) & 7, q = idx & 7;
        float s = 0.f;
        #pragma unroll
        for (int p = 0; p < 8; ++p) s += Cs[p][i] * bufB[t * 64 + p * 8 + q];
        bufA[idx] = s;
    }
    __syncthreads();

    // contract q: out[t][i][j] = sum_q Cs[q][j] * in[t][i][q]; fold 1/8 (mean over c)
    for (int idx = tid; idx < 2048; idx += 256) {
        int t = idx >> 6, i = (idx >> 3) & 7, j = idx & 7;
        float s = 0.f;
        #pragma unroll
        for (int q = 0; q < 8; ++q) s += Cs[q][j] * bufA[t * 64 + i * 8 + q];
        Veff[blockIdx.x * 2048 + idx] = 0.125f * s;
    }
}

// ---------------------------------------------------------------------------
// Kernel 2: xsum[b,s,t,ij] = sum_{c=0..7} x[b, s*256 + c*32 + t, ij]
// One float4 out per thread; wave reads 1 KiB contiguous per instruction.
// ---------------------------------------------------------------------------
__global__ __launch_bounds__(256) void reduce_c_kernel(const float* __restrict__ x,
                                                       float* __restrict__ xsum) {
    int g = blockIdx.x * 256 + threadIdx.x;
    int ij4 = g & 15;
    int t   = (g >> 4) & 31;
    int s   = (g >> 9) & 1;
    int b   = g >> 10;
    const float4* xp = (const float4*)x + ((b * 512 + s * 256 + t) * 16 + ij4);
    float4 acc = make_float4(0.f, 0.f, 0.f, 0.f);
    #pragma unroll
    for (int c = 0; c < 8; ++c) {
        float4 v = xp[c * 32 * 16];
        acc.x += v.x; acc.y += v.y; acc.z += v.z; acc.w += v.w;
    }
    ((float4*)xsum)[g] = acc;
}

// ---------------------------------------------------------------------------
// Kernel 3: feat[b,s,o] = dot(xsum[b,s,:], Veff[s,o,:]) + bias; LeakyReLU.
// Block: 256 thr = (o:64) x (k-quarter:4); 4 batches register-blocked.
// k-tile 256 staged in LDS; Vs pitch 65 float4 (odd) -> even superbank spread.
// Grid (B/4, 2) = 512 blocks, ~70 KiB LDS -> 2 blocks/CU.
// ---------------------------------------------------------------------------
__global__ __launch_bounds__(256) void gemm_kernel(const float* __restrict__ xsum,
                                                   const float* __restrict__ Veff,
                                                   const float* __restrict__ bias,
                                                   float* __restrict__ out) {
    __shared__ float4 Vs4[64 * 65];     // 66560 B
    __shared__ float4 Xs4[4 * 64];      // 4096 B
    __shared__ float  part[4][4][64];   // 4096 B  [kq][b][o]
    const int s   = blockIdx.y;
    const int b0  = blockIdx.x * 4;
    const int tid = threadIdx.x;
    const int o   = tid & 63;
    const int kq  = tid >> 6;

    const float4* xsum4 = (const float4*)xsum;
    const float4* Veff4 = (const float4*)Veff;

    float acc0 = 0.f, acc1 = 0.f, acc2 = 0.f, acc3 = 0.f;

    for (int kt = 0; kt < 8; ++kt) {
        __syncthreads();
        #pragma unroll
        for (int j = 0; j < 16; ++j) {
            int idx = tid + j * 256;                 // 0..4095
            int oo = idx >> 6, k4 = idx & 63;
            Vs4[oo * 65 + k4] = Veff4[(s * 64 + oo) * 512 + kt * 64 + k4];
        }
        {
            int b = tid >> 6, k4 = tid & 63;
            Xs4[tid] = xsum4[((b0 + b) * 2 + s) * 512 + kt * 64 + k4];
        }
        __syncthreads();
        #pragma unroll
        for (int m = 0; m < 16; ++m) {
            int k4 = kq * 16 + m;
            float4 v  = Vs4[o * 65 + k4];
            float4 x0 = Xs4[0 * 64 + k4];
            float4 x1 = Xs4[1 * 64 + k4];
            float4 x2 = Xs4[2 * 64 + k4];
            float4 x3 = Xs4[3 * 64 + k4];
            acc0 += v.x * x0.x + v.y * x0.y + v.z * x0.z + v.w * x0.w;
            acc1 += v.x * x1.x + v.y * x1.y + v.z * x1.z + v.w * x1.w;
            acc2 += v.x * x2.x + v.y * x2.y + v.z * x2.z + v.w * x2.w;
            acc3 += v.x * x3.x + v.y * x3.y + v.z * x3.z + v.w * x3.w;
        }
    }

    part[kq][0][o] = acc0;
    part[kq][1][o] = acc1;
    part[kq][2][o] = acc2;
    part[kq][3][o] = acc3;
    __syncthreads();
    {
        int b = tid >> 6, oo = tid & 63;
        float f = part[0][b][oo] + part[1][b][oo] + part[2][b][oo] + part[3][b][oo]
                + bias[s * 64 + oo];
        f = (f >= 0.f) ? f : SLOPE * f;
        out[(b0 + b) * 128 + s * 64 + oo] = f;
    }
}

extern "C" void kernel_launch(void* const* d_in, const int* in_sizes, int n_in,
                              void* d_out, int out_size, void* d_ws, size_t ws_size,
                              hipStream_t stream) {
    const float* x    = (const float*)d_in[0];   // [B,1,512,8,8]
    const float* W    = (const float*)d_in[1];   // [2,64,32,8,8]
    const float* bias = (const float*)d_in[2];   // [2,64]
    float* out = (float*)d_out;                  // [B,128]

    const int B = in_sizes[0] / (512 * 64);      // 1024

    float* Veff = (float*)d_ws;                  // 2*64*2048 floats = 1 MiB
    float* xsum = Veff + NSW * NF * KDIM;        // B*2*2048 floats = 16 MiB

    veff_kernel<<<NSW * NF, 256, 0, stream>>>(W, Veff);

    int n4 = B * NSW * NDCT * 16;                // 1,048,576 float4 outputs
    reduce_c_kernel<<<n4 / 256, 256, 0, stream>>>(x, xsum);

    gemm_kernel<<<dim3(B / 4, NSW), 256, 0, stream>>>(xsum, Veff, bias, out);
}

// Round 3
// 220.285 us; speedup vs baseline: 1.6200x; 1.0314x over previous
//
#include <hip/hip_runtime.h>

#define NSW 2
#define NDCT 32
#define NF 64
#define KDIM 2048          // 32 t * 64 spatial
#define SLOPE 0.02f
#define PI_F 3.14159265358979323846f

// ---------------------------------------------------------------------------
// Kernel 1: Veff[s,o,t,i,j] = 0.125 * sum_{f,p,q} Ct[f,t] Cs[p,i] Cs[q,j] W[s,o,f,p,q]
// cos tables in LDS, 3 pure-FMA contraction stages. 128 blocks, ~4 us.
// ---------------------------------------------------------------------------
__global__ __launch_bounds__(256) void veff_kernel(const float* __restrict__ W,
                                                   float* __restrict__ Veff) {
    __shared__ float Ct[32][32];   // [f][t] = 2*cos(pi*(2t+1)*f/64)
    __shared__ float Cs[8][8];     // [p][i] = 2*cos(pi*(2i+1)*p/16)
    __shared__ float bufA[2048];
    __shared__ float bufB[2048];
    const int tid = threadIdx.x;

    for (int idx = tid; idx < 1024; idx += 256) {
        int f = idx >> 5, t = idx & 31;
        Ct[f][t] = 2.0f * cosf(PI_F * (float)((2 * t + 1) * f) * (1.0f / 64.0f));
    }
    if (tid < 64) {
        int p = tid >> 3, i = tid & 7;
        Cs[p][i] = 2.0f * cosf(PI_F * (float)((2 * i + 1) * p) * (1.0f / 16.0f));
    }
    const float* Wso = W + blockIdx.x * 2048;   // [f(32)][p(8)][q(8)]
    for (int idx = tid; idx < 2048; idx += 256) bufA[idx] = Wso[idx];
    __syncthreads();

    for (int idx = tid; idx < 2048; idx += 256) {       // contract f
        int t = idx >> 6, pq = idx & 63;
        float s = 0.f;
        #pragma unroll
        for (int f = 0; f < 32; ++f) s += Ct[f][t] * bufA[f * 64 + pq];
        bufB[idx] = s;
    }
    __syncthreads();
    for (int idx = tid; idx < 2048; idx += 256) {       // contract p
        int t = idx >> 6, i = (idx >> 3) & 7, q = idx & 7;
        float s = 0.f;
        #pragma unroll
        for (int p = 0; p < 8; ++p) s += Cs[p][i] * bufB[t * 64 + p * 8 + q];
        bufA[idx] = s;
    }
    __syncthreads();
    for (int idx = tid; idx < 2048; idx += 256) {       // contract q + 1/8
        int t = idx >> 6, i = (idx >> 3) & 7, j = idx & 7;
        float s = 0.f;
        #pragma unroll
        for (int q = 0; q < 8; ++q) s += Cs[q][j] * bufA[t * 64 + i * 8 + q];
        Veff[blockIdx.x * 2048 + idx] = 0.125f * s;
    }
}

// ---------------------------------------------------------------------------
// Kernel 2 (fused): per block = (4 batches, one subwindow s).
//   Phase 1: stream x[b, s*256.., :] (256 KiB) from HBM, c-sum into LDS Xs4.
//   Phase 2: register-blocked GEMM vs LDS-staged Veff k-tiles (128 floats).
// No xsum HBM round-trip. LDS ~69 KiB -> 2 blocks/CU; 512 blocks resident.
// ---------------------------------------------------------------------------
__global__ __launch_bounds__(256) void fused_kernel(const float* __restrict__ x,
                                                    const float* __restrict__ Veff,
                                                    const float* __restrict__ bias,
                                                    float* __restrict__ out) {
    __shared__ float4 Xs4[4 * 512];     // [b][k4], k4 = t*16+ij4  (32 KiB)
    __shared__ float4 Vs4[64 * 33];     // 64 o x 32 f4, pitch 33  (33 KiB)
    __shared__ float  part[4][4][64];   // [kq][b][o]              (4 KiB)
    const int s   = blockIdx.y;
    const int b0  = blockIdx.x * 4;
    const int tid = threadIdx.x;

    // ---- Phase 1: xsum[b, t, ij] = sum_c x[b, s*256 + c*32 + t, ij] ----
    const float4* xbase = (const float4*)x;
    #pragma unroll
    for (int b = 0; b < 4; ++b) {
        #pragma unroll
        for (int r = 0; r < 2; ++r) {
            int k4 = tid + r * 256;                       // 0..511
            const float4* xp = xbase + (((size_t)(b0 + b) * 512 + s * 256) * 16 + k4);
            float4 acc = make_float4(0.f, 0.f, 0.f, 0.f);
            #pragma unroll
            for (int c = 0; c < 8; ++c) {
                float4 v = xp[c * 512];                   // c stride = 32 tp * 16 f4
                acc.x += v.x; acc.y += v.y; acc.z += v.z; acc.w += v.w;
            }
            Xs4[b * 512 + k4] = acc;
        }
    }

    // ---- Phase 2: feat[b,o] = dot(xsum[b,:], Veff[s,o,:]) ----
    const int o  = tid & 63;
    const int kq = tid >> 6;
    const float4* Veff4 = (const float4*)Veff + (size_t)s * 64 * 512;

    float acc0 = 0.f, acc1 = 0.f, acc2 = 0.f, acc3 = 0.f;
    for (int kt = 0; kt < 16; ++kt) {                     // 16 tiles x 32 f4
        __syncthreads();                                  // (1st also guards Xs4)
        #pragma unroll
        for (int j = 0; j < 8; ++j) {
            int idx = tid + j * 256;                      // 0..2047
            int oo = idx >> 5, k4 = idx & 31;
            Vs4[oo * 33 + k4] = Veff4[oo * 512 + kt * 32 + k4];
        }
        __syncthreads();
        #pragma unroll
        for (int m = 0; m < 8; ++m) {
            int k4 = kq * 8 + m;
            float4 v  = Vs4[o * 33 + k4];                 // stride 132 dw: uniform banks
            float4 x0 = Xs4[0 * 512 + kt * 32 + k4];      // broadcast within wave
            float4 x1 = Xs4[1 * 512 + kt * 32 + k4];
            float4 x2 = Xs4[2 * 512 + kt * 32 + k4];
            float4 x3 = Xs4[3 * 512 + kt * 32 + k4];
            acc0 += v.x * x0.x + v.y * x0.y + v.z * x0.z + v.w * x0.w;
            acc1 += v.x * x1.x + v.y * x1.y + v.z * x1.z + v.w * x1.w;
            acc2 += v.x * x2.x + v.y * x2.y + v.z * x2.z + v.w * x2.w;
            acc3 += v.x * x3.x + v.y * x3.y + v.z * x3.z + v.w * x3.w;
        }
    }

    part[kq][0][o] = acc0;
    part[kq][1][o] = acc1;
    part[kq][2][o] = acc2;
    part[kq][3][o] = acc3;
    __syncthreads();
    {
        int b = tid >> 6, oo = tid & 63;
        float f = part[0][b][oo] + part[1][b][oo] + part[2][b][oo] + part[3][b][oo]
                + bias[s * 64 + oo];
        f = (f >= 0.f) ? f : SLOPE * f;
        out[(size_t)(b0 + b) * 128 + s * 64 + oo] = f;
    }
}

extern "C" void kernel_launch(void* const* d_in, const int* in_sizes, int n_in,
                              void* d_out, int out_size, void* d_ws, size_t ws_size,
                              hipStream_t stream) {
    const float* x    = (const float*)d_in[0];   // [B,1,512,8,8]
    const float* W    = (const float*)d_in[1];   // [2,64,32,8,8]
    const float* bias = (const float*)d_in[2];   // [2,64]
    float* out = (float*)d_out;                  // [B,128]

    const int B = in_sizes[0] / (512 * 64);      // 1024

    float* Veff = (float*)d_ws;                  // 2*64*2048 floats = 1 MiB

    veff_kernel<<<NSW * NF, 256, 0, stream>>>(W, Veff);
    fused_kernel<<<dim3(B / 4, NSW), 256, 0, stream>>>(x, Veff, bias, out);
}